// Round 8
// baseline (248.416 us; speedup 1.0000x reference)
//
#include <hip/hip_runtime.h>
#include <cstdint>
#include <cstddef>

#define BPTS    131072
#define D_DIM   128
#define G_GR    128
#define NL      8
#define NSLC    16                 // slices per group -> 2048 heavy blocks
#define PERMBUF 128                // max slice len ~72 (count ~1024±32, /16)
#define NBLK_S  64                 // sort blocks
#define PPB     (BPTS / NBLK_S)    // 2048 contiguous points per sort block

// d += dpp_shifted(d); pure VALU. Used only in k_final (not hot).
__device__ __forceinline__ float dpp_add(float d, const int ctrl) {
    int s;
    switch (ctrl) {   // ctrl must be an ICE for the builtin
    case 0x111: s = __builtin_amdgcn_update_dpp(0, __float_as_int(d), 0x111, 0xf, 0xf, true); break;
    case 0x112: s = __builtin_amdgcn_update_dpp(0, __float_as_int(d), 0x112, 0xf, 0xf, true); break;
    case 0x114: s = __builtin_amdgcn_update_dpp(0, __float_as_int(d), 0x114, 0xf, 0xf, true); break;
    case 0x118: s = __builtin_amdgcn_update_dpp(0, __float_as_int(d), 0x118, 0xf, 0xf, true); break;
    case 0x142: s = __builtin_amdgcn_update_dpp(0, __float_as_int(d), 0x142, 0xf, 0xf, true); break;
    default:    s = __builtin_amdgcn_update_dpp(0, __float_as_int(d), 0x143, 0xf, 0xf, true); break;
    }
    return d + __int_as_float(s);
}

// full 64-lane sum -> result valid in lane 63
__device__ __forceinline__ float sum64(float d) {
    d = dpp_add(d, 0x111);
    d = dpp_add(d, 0x112);
    d = dpp_add(d, 0x114);
    d = dpp_add(d, 0x118);
    d = dpp_add(d, 0x142);
    d = dpp_add(d, 0x143);
    return d;
}

// ---------------------------------------------------------------------------
// k_hist: per-block histogram of group ids -> hblk[blk][128]   (R0 exact)
// ---------------------------------------------------------------------------
__global__ __launch_bounds__(256) void k_hist(const int* __restrict__ sub,
                                              const int* __restrict__ lab,
                                              int* __restrict__ hblk) {
    __shared__ int h[G_GR];
    int t = threadIdx.x, blk = blockIdx.x;
    if (t < G_GR) h[t] = 0;
    __syncthreads();
    int b0 = blk * PPB;
    for (int i = t; i < PPB; i += 256)
        atomicAdd(&h[sub[b0 + i] * NL + lab[b0 + i]], 1);
    __syncthreads();
    if (t < G_GR) hblk[blk * G_GR + t] = h[t];
}

// ---------------------------------------------------------------------------
// k_scatter: fused prefix + scatter via per-block LDS cursor.   (R0 exact)
// ---------------------------------------------------------------------------
__global__ __launch_bounds__(256) void k_scatter(const int* __restrict__ sub,
                                                 const int* __restrict__ lab,
                                                 const int* __restrict__ hblk,
                                                 int* __restrict__ counts,
                                                 int* __restrict__ offsets,
                                                 float* __restrict__ countsf,
                                                 int* __restrict__ perm) {
    __shared__ int tot[G_GR];
    __shared__ int cur[G_GR];
    int t = threadIdx.x, blk = blockIdx.x;
    if (t < G_GR) {
        int tt = 0, mine = 0;
        for (int b = 0; b < NBLK_S; ++b) {
            int v = hblk[b * G_GR + t];
            tt += v;
            if (b < blk) mine += v;
        }
        tot[t] = tt;
        cur[t] = mine;
    }
    __syncthreads();
    if (t < G_GR) {
        int off = 0;
        for (int j = 0; j < t; ++j) off += tot[j];
        cur[t] += off;
        if (blk == 0) {
            counts[t]  = tot[t];
            offsets[t] = off;
            countsf[t] = 2.0f * (float)tot[t];
        }
    }
    __syncthreads();
    int b0 = blk * PPB;
    for (int i = t; i < PPB; i += 256) {
        int p = b0 + i;
        int g = sub[p] * NL + lab[p];
        int s = atomicAdd(&cur[g], 1);   // LDS-only cursor
        perm[s] = p;
    }
}

// ---------------------------------------------------------------------------
// k_psum: block (g,s) sums its slice of group g. Wave-per-point, batched
// unroll-8 float4 loads, register accumulate, zero atomics.     (R0 exact)
// ---------------------------------------------------------------------------
__global__ __launch_bounds__(256) void k_psum(const float4* __restrict__ X4,
                                              const int* __restrict__ perm,
                                              const int* __restrict__ offsets,
                                              const int* __restrict__ counts,
                                              float* __restrict__ part) {
    __shared__ int   pbuf[PERMBUF];
    __shared__ float red[4 * 256];
    int g = blockIdx.x >> 4, s = blockIdx.x & 15;
    int off = offsets[g], len = counts[g];
    int lo = off + (len * s) / NSLC;
    int hi = off + (len * (s + 1)) / NSLC;
    int slen = hi - lo;
    int t = threadIdx.x, lane = t & 63, w = t >> 6;

    for (int j = t; j < slen; j += 256) pbuf[j] = perm[lo + j];
    __syncthreads();

    float4 acc = make_float4(0.f, 0.f, 0.f, 0.f);
    for (int i = w * 8; i < slen; i += 32) {
        int idx[8];
#pragma unroll
        for (int u = 0; u < 8; ++u) {
            int j = i + u;
            idx[u] = pbuf[(j < slen) ? j : (slen - 1)];
        }
        float4 x[8];
#pragma unroll
        for (int u = 0; u < 8; ++u) x[u] = X4[(size_t)idx[u] * 64 + lane];
#pragma unroll
        for (int u = 0; u < 8; ++u) {
            if (i + u < slen) {
                acc.x += x[u].x; acc.y += x[u].y;
                acc.z += x[u].z; acc.w += x[u].w;
            }
        }
    }
    red[w * 256 + lane * 4 + 0] = acc.x;
    red[w * 256 + lane * 4 + 1] = acc.y;
    red[w * 256 + lane * 4 + 2] = acc.z;
    red[w * 256 + lane * 4 + 3] = acc.w;
    __syncthreads();
    if (t < 128) {                        // fold 4 wave copies + the two views
        float v = 0.f;
        for (int r = 0; r < 4; ++r)
            v += red[r * 256 + t] + red[r * 256 + t + 128];
        part[(size_t)blockIdx.x * 128 + t] = v;
    }
}

// ---------------------------------------------------------------------------
// k_dist: fused centroid reduce + per-point ||x-c|| via 32-lane shfl
// butterfly (R0 exact — proven faster than the DPP chain in R7 A/B).
// ---------------------------------------------------------------------------
__global__ __launch_bounds__(256) void k_dist(const float4* __restrict__ X4,
                                              const int* __restrict__ perm,
                                              const int* __restrict__ offsets,
                                              const int* __restrict__ counts,
                                              const float* __restrict__ part,
                                              float* __restrict__ centroid,
                                              float* __restrict__ dpart) {
    __shared__ int   pbuf[PERMBUF];
    __shared__ float cen[D_DIM];
    __shared__ float wsum[4];
    int g = blockIdx.x >> 4, s = blockIdx.x & 15;
    int off = offsets[g], len = counts[g];
    int lo = off + (len * s) / NSLC;
    int hi = off + (len * (s + 1)) / NSLC;
    int slen = hi - lo;
    int t = threadIdx.x, lane = t & 63, w = t >> 6;

    if (t < D_DIM) {                      // fused centroid reduce
        float v = 0.f;
        for (int s2 = 0; s2 < NSLC; ++s2)
            v += part[(size_t)(g * NSLC + s2) * 128 + t];
        float c = (len > 0) ? v / (2.0f * (float)len) : 0.f;
        cen[t] = c;
        if (s == 0) centroid[g * D_DIM + t] = c;
    }
    for (int j = t; j < slen; j += 256) pbuf[j] = perm[lo + j];
    __syncthreads();

    int cd = (lane & 31) * 4;
    float4 c = make_float4(cen[cd], cen[cd + 1], cen[cd + 2], cen[cd + 3]);

    float sacc = 0.f;
    for (int i = w * 8; i < slen; i += 32) {
        int idx[8];
#pragma unroll
        for (int u = 0; u < 8; ++u) {
            int j = i + u;
            idx[u] = pbuf[(j < slen) ? j : (slen - 1)];
        }
        float4 x[8];
#pragma unroll
        for (int u = 0; u < 8; ++u) x[u] = X4[(size_t)idx[u] * 64 + lane];
#pragma unroll
        for (int u = 0; u < 8; ++u) {
            float dx = x[u].x - c.x, dy = x[u].y - c.y;
            float dz = x[u].z - c.z, dw = x[u].w - c.w;
            float d = dx * dx + dy * dy + dz * dz + dw * dw;
#pragma unroll
            for (int m = 1; m <= 16; m <<= 1) d += __shfl_xor(d, m);
            if (i + u < slen) sacc += sqrtf(sqrtf(d));   // sqrt(||x-c||)
        }
    }
    float t2 = sacc + __shfl_xor(sacc, 32);   // fold the two views
    if (lane == 0) wsum[w] = t2;
    __syncthreads();
    if (t == 0) dpart[blockIdx.x] = wsum[0] + wsum[1] + wsum[2] + wsum[3];
}

// ---------------------------------------------------------------------------
// k_final: single block, 512 threads (only change vs R0). Parallel dpart
// fold, percentile/clip, coc via 4-slice coalesced reduce, dot via 8 waves
// x DPP sum64 (no uncoalesced per-thread row walk).
// ---------------------------------------------------------------------------
__global__ __launch_bounds__(512) void k_final(const float* __restrict__ dpart,
                                               const float* __restrict__ countsf,
                                               const float* __restrict__ centroid,
                                               float* __restrict__ out) {
    __shared__ float sl4[4][G_GR];
    __shared__ float srt[G_GR];
    __shared__ float red[G_GR];
    __shared__ float cocs[D_DIM];
    __shared__ float dotv[G_GR];
    int t = threadIdx.x;
    int col = t & 127, q = t >> 7;            // 4 slices
    int lane = t & 63, w8 = t >> 6;           // 8 waves

    float dens = 0.f, cnt = 0.f;
    if (t < G_GR) {
        float ds = 0.f;
        for (int s = 0; s < NSLC; ++s) ds += dpart[t * NSLC + s];
        cnt = countsf[t];
        dens = (cnt > 1.f) ? (ds / cnt) / logf(cnt + 10.f) : 0.f;
        red[t] = dens;
    }
    __syncthreads();
    for (int s = 64; s > 0; s >>= 1) {
        if (t < s) red[t] = fmaxf(red[t], red[t + s]);
        __syncthreads();
    }
    float dmax = red[0];
    __syncthreads();
    if (t < G_GR && !(cnt > 1.f)) dens = dmax;

    // bitonic sort ascending over 128 entries
    if (t < G_GR) srt[t] = dens;
    __syncthreads();
    for (int k = 2; k <= G_GR; k <<= 1) {
        for (int j = k >> 1; j > 0; j >>= 1) {
            int ixj = t ^ j;
            if (t < G_GR && ixj > t) {
                float a = srt[t], b = srt[ixj];
                bool up = ((t & k) == 0);
                if ((a > b) == up) { srt[t] = b; srt[ixj] = a; }
            }
            __syncthreads();
        }
    }
    double p10 = 0.10 * 127.0, p90 = 0.90 * 127.0;
    int   i10 = (int)p10,           i90 = (int)p90;
    float f10 = (float)(p10 - i10), f90 = (float)(p90 - i90);
    float lo = srt[i10] + f10 * (srt[i10 + 1] - srt[i10]);
    float hi = srt[i90] + f90 * (srt[i90 + 1] - srt[i90]);
    if (t < G_GR) dens = fminf(fmaxf(dens, lo), hi);

    if (t < G_GR) red[t] = dens;
    __syncthreads();
    for (int s = 64; s > 0; s >>= 1) {
        if (t < s) red[t] += red[t + s];
        __syncthreads();
    }
    float dmean = red[0] / 128.f;
    __syncthreads();

    // coc: 4-slice coalesced column sum
    float cs = 0.f;
    for (int g = q; g < G_GR; g += 4) cs += centroid[g * D_DIM + col];
    sl4[q][col] = cs;
    __syncthreads();
    if (t < D_DIM)
        cocs[t] = (sl4[0][t] + sl4[1][t] + sl4[2][t] + sl4[3][t]) / 128.f;
    __syncthreads();

    // dot: 8 waves x 16 groups, DPP sum64 per group (coalesced loads)
    {
        float2 co = *(const float2*)&cocs[2 * lane];
        for (int i = 0; i < 16; ++i) {
            int g = w8 * 16 + i;
            float2 c = *(const float2*)(centroid + (size_t)g * D_DIM + 2 * lane);
            float p = c.x * co.x + c.y * co.y;
            float sm = sum64(p);
            if (lane == 63) dotv[g] = sm;
        }
    }
    __syncthreads();

    float sim = 0.f;
    if (t < G_GR) {
        float dv = 0.1f * dens / dmean;
        sim = expf(dotv[t] / dv);
        red[t] = sim;
    }
    __syncthreads();
    for (int s = 64; s > 0; s >>= 1) {
        if (t < s) red[t] = fmaxf(red[t], red[t + s]);
        __syncthreads();
    }
    float smax = red[0];
    __syncthreads();
    if (t < G_GR) red[t] = sim - smax;
    __syncthreads();
    for (int s = 64; s > 0; s >>= 1) {
        if (t < s) red[t] += red[t + s];
        __syncthreads();
    }
    if (t == 0) out[0] = -(red[0] / 128.f);
}

// ---------------------------------------------------------------------------
extern "C" void kernel_launch(void* const* d_in, const int* in_sizes, int n_in,
                              void* d_out, int out_size, void* d_ws, size_t ws_size,
                              hipStream_t stream) {
    const float4* X4      = (const float4*)d_in[0];
    const int*    subject = (const int*)d_in[1];
    const int*    labels  = (const int*)d_in[2];
    float*        out     = (float*)d_out;
    char*         ws      = (char*)d_ws;

    size_t o = 0;
    int*   hblk     = (int*)(ws + o);   o += (size_t)NBLK_S * G_GR * 4;     // 32 KiB
    int*   counts   = (int*)(ws + o);   o += 512;
    int*   offsets  = (int*)(ws + o);   o += 512;
    float* countsf  = (float*)(ws + o); o += 512;
    int*   perm     = (int*)(ws + o);   o += (size_t)BPTS * 4;              // 512 KiB
    float* part     = (float*)(ws + o); o += (size_t)G_GR * NSLC * 128 * 4; // 1 MiB
    float* centroid = (float*)(ws + o); o += (size_t)G_GR * D_DIM * 4;      // 64 KiB
    float* dpart    = (float*)(ws + o); o += (size_t)G_GR * NSLC * 4;       // 8 KiB

    k_hist   <<<NBLK_S, 256, 0, stream>>>(subject, labels, hblk);
    k_scatter<<<NBLK_S, 256, 0, stream>>>(subject, labels, hblk, counts, offsets, countsf, perm);
    k_psum   <<<G_GR * NSLC, 256, 0, stream>>>(X4, perm, offsets, counts, part);
    k_dist   <<<G_GR * NSLC, 256, 0, stream>>>(X4, perm, offsets, counts, part, centroid, dpart);
    k_final  <<<1, 512, 0, stream>>>(dpart, countsf, centroid, out);
}